// Round 11
// baseline (1264.340 us; speedup 1.0000x reference)
//
#include <hip/hip_runtime.h>
#include <math.h>
#include <stdint.h>

// SLAYER 2-layer SNN. Round 11: barrier-free gemm (A-frags direct from global,
// pre-swizzled into MFMA register order), higher occupancy (launch_bounds 3).
//   bitifyT -> decompose_i8 x2 (swizzled layout) ->
//   fused_gc<1024> (bits1 -> u) -> scan<BITS> (u -> bitsH) ->
//   fused_gc<2048> (bitsH -> u) -> scan<F32>  (u -> f32 out).
// R10 diagnosis: fused_gc 2 waves/SIMD (VGPR 196) + 16 barrier drains/block in
// the K-loop -> 15% issue efficiency. R11: A-fragments are wave-independent and
// per-lane-indexed -> load straight from global (one coalesced dwordx4 per
// frag, L2-hot across 32 b-blocks), no LDS staging, ZERO barriers in the
// K-loop; LDS 35.5 KB; launch_bounds(256,3) targets 3 blocks/CU.
// Numerics byte-identical to R10 (absmax 0.0): i8 digit planes (exact),
// i32 MFMA accum, fp64 recombine/conv/scan with fp32-rounded taps.

#define TT     256
#define KLEN   62
#define THETA  10.0

typedef int v4i __attribute__((ext_vector_type(4)));

// ============================ bitify (transposed) ===========================
// x: [32][1024][256] f32 {0,1}; bitsT: [b][32 words][256 t]
__global__ __launch_bounds__(256)
void bitifyT(const float* __restrict__ x, uint32_t* __restrict__ bitsT)
{
    const int b  = blockIdx.x;
    const int ig = blockIdx.y;            // group of 128 inputs (4 words)
    const int t  = threadIdx.x;
    const float* xp = x     + ((size_t)b*1024 + ig*128)*TT + t;
    uint32_t*    bp = bitsT + ((size_t)b*32 + ig*4)*TT + t;
    for (int wi = 0; wi < 4; ++wi) {
        uint32_t wb = 0;
        #pragma unroll
        for (int j = 0; j < 32; ++j)
            wb |= (xp[(size_t)(wi*32 + j)*TT] >= 0.5f) ? (1u << j) : 0u;
        bp[(size_t)wi * TT] = wb;
    }
}

// ====================== weight -> int8 digit planes (swizzled) ==============
// planes: [oblk][s(I/64)][p(5)][lane(64)][16 B] -- MFMA A-frag register order:
// lane = quad*16+col holds digits of w[oblk*16+col][s*64 + quad*16 + 0..15].
__global__ __launch_bounds__(256)
void decompose_i8(const float* __restrict__ w, signed char* __restrict__ planes,
                  int I, int total)
{
    const int f = blockIdx.x * 256 + threadIdx.x;
    if (f >= total) return;
    const int NS = I / 64;
    const int per_oblk = NS * 5120;
    int rem  = f;
    const int oblk = rem / per_oblk;  rem -= oblk * per_oblk;
    const int s    = rem / 5120;      rem -= s * 5120;
    const int p    = rem >> 10;
    const int l    = (rem & 1023) >> 4;
    const int j    = rem & 15;
    const int quad = l >> 4, col = l & 15;
    const float wv = w[(size_t)(oblk*16 + col) * I + s*64 + quad*16 + j];
    long long v = llrint((double)wv * 274877906944.0);   // w * 2^38, exact int
    int d = 0;
    for (int q = 0; q <= p; ++q) {                       // balanced base-256
        d = (int)((v + 128) & 255) - 128;
        v = (v - d) >> 8;
    }
    planes[f] = (signed char)d;
}

// ====================== fused gemm+conv kernel ==============================
// grid (O/16, B). Per block: barrier-free i8 MFMA gemm over all 256 t ->
// exact fp64 a in LDS -> 61-tap FIR conv from LDS -> coalesced u stores.
template<int I>
__global__ __launch_bounds__(256, 3)
void fused_gc(const uint32_t*    __restrict__ bitsT,   // [B][I/32][256]
              const signed char* __restrict__ planes,  // swizzled A planes
              double*            __restrict__ u,       // [B][256][OS]
              int OS)
{
    constexpr int IW = I / 32;
    constexpr int NS = I / 64;
    __shared__ double a_lds[257 * 17];                   // 34.95 KB (row 256 = 0)
    __shared__ double srmE[68];

    const int tid  = threadIdx.x;
    const int lane = tid & 63;
    const int wvu  = tid >> 6;
    const int quad = lane >> 4;
    const int col  = lane & 15;
    const int b    = blockIdx.y;
    const int oblk = blockIdx.x;
    const int o0   = oblk * 16;
    const int tw   = wvu * 64;

    if (tid < 68) {
        const int k = tid - 2;
        double v = 0.0;
        if (k >= 1 && k <= 61) {
            double wv = (double)k / 8.0 * exp(1.0 - (double)k / 8.0);
            v = (double)(float)wv;     // fp32-rounded tap, widened (R1-R10)
        }
        srmE[tid] = v;
    }

    // ---------------- gemm: 5 i8 digit planes, K=64, NO barriers ------------
    const signed char* Apg = planes + (size_t)oblk * NS * 5120 + lane * 16;
    const uint32_t*    bw  = bitsT + (size_t)b * IW * 256 + tw + col;

    v4i acc[5][4];
    #pragma unroll
    for (int p = 0; p < 5; ++p)
        #pragma unroll
        for (int nt = 0; nt < 4; ++nt)
            acc[p][nt] = (v4i){0, 0, 0, 0};

    #pragma unroll 2
    for (int s = 0; s < NS; ++s) {
        uint32_t m0[4], m1[4];
        #pragma unroll
        for (int nt = 0; nt < 4; ++nt) {
            m0[nt] = bw[(size_t)(2*s)     * 256 + nt * 16];
            m1[nt] = bw[(size_t)(2*s + 1) * 256 + nt * 16];
        }
        v4i af[5];
        #pragma unroll
        for (int p = 0; p < 5; ++p)
            af[p] = *(const v4i*)(const void*)(Apg + (size_t)s * 5120 + p * 1024);

        #pragma unroll
        for (int nt = 0; nt < 4; ++nt) {
            const uint32_t sel = (quad & 2) ? m1[nt] : m0[nt];
            const uint32_t h   = (sel >> ((quad & 1) * 16)) & 0xFFFFu;
            union { uint32_t uu[4]; v4i v; } bf;
            #pragma unroll
            for (int j = 0; j < 4; ++j) {
                const uint32_t n = (h >> (4*j)) & 0xFu;
                bf.uu[j] = (n * 0x00204081u) & 0x01010101u;  // 4 bits -> 4 i8 {0,1}
            }
            #pragma unroll
            for (int p = 0; p < 5; ++p)
                acc[p][nt] = __builtin_amdgcn_mfma_i32_16x16x64_i8(
                                 af[p], bf.v, acc[p][nt], 0, 0, 0);
        }
    }

    // ---------------- recombine: exact fp64 a into LDS (verified) -----------
    const double inv = 1.0 / 274877906944.0;             // 2^-38
    #pragma unroll
    for (int nt = 0; nt < 4; ++nt) {
        const int t = tw + nt*16 + col;
        #pragma unroll
        for (int r = 0; r < 4; ++r) {
            double v =            (double)acc[4][nt][r];
            v = v * 256.0 + (double)acc[3][nt][r];
            v = v * 256.0 + (double)acc[2][nt][r];
            v = v * 256.0 + (double)acc[1][nt][r];
            v = v * 256.0 + (double)acc[0][nt][r];
            a_lds[t * 17 + quad*4 + r] = v * inv;
        }
    }
    if (tid < 17) a_lds[256 * 17 + tid] = 0.0;           // zero-guard row
    __syncthreads();                                     // the only barrier

    // ---------------- conv: 61-tap FIR from LDS (verified) ------------------
    const int o    = tid & 15;
    const int tgrp = tid >> 4;                           // 0..15
    #pragma unroll
    for (int pass = 0; pass < 4; ++pass) {
        const int T0b = pass * 64 + tgrp * 4;
        double u0 = 0, u1 = 0, u2 = 0, u3 = 0;
        double w1 = srmE[64], w2 = srmE[65], w3 = srmE[66];   // zero pads
        for (int d = 0; d < 64; d += 4) {
            const int row = T0b - 61 + d;
            const int r0 = (row + 0 < 0) ? 256 : row + 0;
            const int r1 = (row + 1 < 0) ? 256 : row + 1;
            const int r2 = (row + 2 < 0) ? 256 : row + 2;
            const int r3 = (row + 3 < 0) ? 256 : row + 3;
            const double av0 = a_lds[r0 * 17 + o];
            const double av1 = a_lds[r1 * 17 + o];
            const double av2 = a_lds[r2 * 17 + o];
            const double av3 = a_lds[r3 * 17 + o];
            const double n0 = srmE[63 - d], n1 = srmE[62 - d];
            const double n2 = srmE[61 - d], n3 = srmE[60 - d];
            u0 = fma(n0, av0, u0); u1 = fma(w1, av0, u1); u2 = fma(w2, av0, u2); u3 = fma(w3, av0, u3);
            u0 = fma(n1, av1, u0); u1 = fma(n0, av1, u1); u2 = fma(w1, av1, u2); u3 = fma(w2, av1, u3);
            u0 = fma(n2, av2, u0); u1 = fma(n1, av2, u1); u2 = fma(n0, av2, u2); u3 = fma(w1, av2, u3);
            u0 = fma(n3, av3, u0); u1 = fma(n2, av3, u1); u2 = fma(n1, av3, u2); u3 = fma(n0, av3, u3);
            w1 = n3; w2 = n2; w3 = n1;
        }
        double* up = u + ((size_t)b * 256 + T0b) * OS + o0 + o;
        up[0]              = u0;
        up[(size_t)OS]     = u1;
        up[(size_t)OS * 2] = u2;
        up[(size_t)OS * 3] = u3;
    }
}

// ========================== scan (R8/R10-verified) ==========================
// lane = neuron; 256 sequential steps; refractory via 61-bit history mask.
// FINAL=false: ballots -> bitsT_out[b][word][t]. FINAL=true: f32 out[b][o][t].
template<bool FINAL>
__global__ __launch_bounds__(256)
void scan_spikes(const double* __restrict__ u, uint32_t* __restrict__ bitsT_out,
                 float* __restrict__ f32_out, int OS, int OW)
{
    __shared__ double   ref64[KLEN];
    __shared__ uint32_t blds[8][256];   // 8 KB ballot staging
    const int tid = threadIdx.x;
    if (tid < KLEN) {
        double v = (double)tid / 8.0 * exp(1.0 - (double)tid / 8.0);
        ref64[tid] = (double)(float)(-20.0 * v);
    }
    __syncthreads();

    const int b     = blockIdx.y;
    const int obase = blockIdx.x * 256;
    const int o     = obase + tid;
    const int lane  = tid & 63;
    const int wv    = tid >> 6;
    const double* up = u + (size_t)b * TT * OS + o;

    uint64_t mask = 0;
    double cur0 = up[0], cur1 = up[OS], cur2 = up[2 * (size_t)OS], cur3 = up[3 * (size_t)OS];
    for (int t0 = 0; t0 < TT; t0 += 4) {
        double nx0 = 0, nx1 = 0, nx2 = 0, nx3 = 0;
        if (t0 + 4 < TT) {
            const double* pp = up + (size_t)(t0 + 4) * OS;
            nx0 = pp[0]; nx1 = pp[OS]; nx2 = pp[2 * (size_t)OS]; nx3 = pp[3 * (size_t)OS];
        }
        #pragma unroll
        for (int q = 0; q < 4; ++q) {
            const double uv = (q == 0) ? cur0 : (q == 1) ? cur1 : (q == 2) ? cur2 : cur3;
            uint64_t m = mask;
            double r0 = 0.0, r1 = 0.0;
            while (m) {
                int p = __builtin_ctzll(m); m &= m - 1;
                r0 += ref64[p + 1];
                if (m) { int pq = __builtin_ctzll(m); m &= m - 1; r1 += ref64[pq + 1]; }
            }
            const bool s = (uv + (r0 + r1)) >= THETA;
            const uint64_t bal = __ballot(s);
            if (lane == 0) {
                blds[wv * 2 + 0][t0 + q] = (uint32_t)bal;
                blds[wv * 2 + 1][t0 + q] = (uint32_t)(bal >> 32);
            }
            mask = ((mask << 1) | (s ? 1ull : 0ull)) & ((1ull << 61) - 1ull);
        }
        cur0 = nx0; cur1 = nx1; cur2 = nx2; cur3 = nx3;
    }
    __syncthreads();

    if (!FINAL) {
        const int wordbase = obase >> 5;
        for (int e = tid; e < 8 * 256; e += 256) {
            const int wl = e >> 8, t = e & 255;
            bitsT_out[((size_t)b * OW + wordbase + wl) * TT + t] = blds[wl][t];
        }
    } else {
        for (int ol = 0; ol < 256; ++ol) {
            const uint32_t w = blds[ol >> 5][tid];
            f32_out[((size_t)b * 512 + obase + ol) * TT + tid] =
                (float)((w >> (ol & 31)) & 1u);
        }
    }
}

// ================================ launcher ==================================
extern "C" void kernel_launch(void* const* d_in, const int* in_sizes, int n_in,
                              void* d_out, int out_size, void* d_ws, size_t ws_size,
                              hipStream_t stream)
{
    const float* x  = (const float*)d_in[0];   // [32][1024][256]
    const float* w1 = (const float*)d_in[1];   // [2048][1024]
    const float* w2 = (const float*)d_in[2];   // [512][2048]
    float* out = (float*)d_out;                // [32][512][256]

    char* ws = (char*)d_ws;
    uint32_t* bits1 = (uint32_t*)ws;                        // 1 MB
    uint32_t* bitsH = (uint32_t*)(ws + (size_t)1048576);    // 2 MB
    size_t off = 1048576 + 2097152;
    signed char* P1 = (signed char*)(ws + off);             // 128*16*5120 = 10.5 MB
    off += (size_t)128 * 16 * 5120;
    signed char* P2 = (signed char*)(ws + off);             // 32*32*5120  = 5.24 MB
    off += (size_t)32 * 32 * 5120;
    off = (off + 255) & ~(size_t)255;
    double* uBuf = (double*)(ws + off);                     // 32*256*2048*8 = 134 MB

    bitifyT<<<dim3(32, 8), 256, 0, stream>>>(x, bits1);
    decompose_i8<<<dim3((10485760 + 255)/256), 256, 0, stream>>>(w1, P1, 1024, 10485760);
    decompose_i8<<<dim3((5242880  + 255)/256), 256, 0, stream>>>(w2, P2, 2048, 5242880);

    // layer 1: 1024 -> 2048
    fused_gc<1024><<<dim3(128, 32), 256, 0, stream>>>(bits1, P1, uBuf, 2048);
    scan_spikes<false><<<dim3(8, 32), 256, 0, stream>>>(uBuf, bitsH, nullptr, 2048, 64);
    // layer 2: 2048 -> 512
    fused_gc<2048><<<dim3(32, 32), 256, 0, stream>>>(bitsH, P2, uBuf, 512);
    scan_spikes<true><<<dim3(2, 32), 256, 0, stream>>>(uBuf, nullptr, out, 512, 16);
}

// Round 12
// 682.853 us; speedup vs baseline: 1.8516x; 1.8516x over previous
//
#include <hip/hip_runtime.h>
#include <math.h>
#include <stdint.h>

// SLAYER 2-layer SNN. Round 12: R11 structure with the two bugs fixed.
//   bitifyT -> decompose_i8 x2 (MFMA-register-order planes) ->
//   fused_gc<1024> (bits1 -> u) -> scan<BITS> (u -> bitsH) ->
//   fused_gc<2048> (bitsH -> u) -> scan<F32>  (u -> f32 out).
// R11 post-mortem: __launch_bounds__(256,3) mis-sized the allocator to 84
// VGPR -> acc[5][4] spilled to scratch (WRITE 1.64 GB, FETCH 890 MB); grid
// order (oblk fastest) spread same-oblk blocks 128 apart -> per-XCD A-plane
// working set ~8 MB > 4 MB L2 -> no reuse. R12: default launch_bounds (R10
// proved 196 VGPR spill-free), grid (b fastest, oblk slow) -> 32 same-oblk
// blocks dispatch-adjacent -> A-planes L2-hot. Zero K-loop barriers kept.
// Numerics byte-identical to R10/R11 (absmax 0.0): exact i8 digit planes,
// i32 MFMA accum, fp64 recombine/conv/scan with fp32-rounded taps.

#define TT     256
#define KLEN   62
#define THETA  10.0

typedef int v4i __attribute__((ext_vector_type(4)));

// ============================ bitify (transposed) ===========================
// x: [32][1024][256] f32 {0,1}; bitsT: [b][32 words][256 t]
__global__ __launch_bounds__(256)
void bitifyT(const float* __restrict__ x, uint32_t* __restrict__ bitsT)
{
    const int b  = blockIdx.x;
    const int ig = blockIdx.y;            // group of 128 inputs (4 words)
    const int t  = threadIdx.x;
    const float* xp = x     + ((size_t)b*1024 + ig*128)*TT + t;
    uint32_t*    bp = bitsT + ((size_t)b*32 + ig*4)*TT + t;
    for (int wi = 0; wi < 4; ++wi) {
        uint32_t wb = 0;
        #pragma unroll
        for (int j = 0; j < 32; ++j)
            wb |= (xp[(size_t)(wi*32 + j)*TT] >= 0.5f) ? (1u << j) : 0u;
        bp[(size_t)wi * TT] = wb;
    }
}

// ====================== weight -> int8 digit planes (swizzled) ==============
// planes: [oblk][s(I/64)][p(5)][lane(64)][16 B] -- MFMA A-frag register order:
// lane = quad*16+col holds digits of w[oblk*16+col][s*64 + quad*16 + 0..15].
__global__ __launch_bounds__(256)
void decompose_i8(const float* __restrict__ w, signed char* __restrict__ planes,
                  int I, int total)
{
    const int f = blockIdx.x * 256 + threadIdx.x;
    if (f >= total) return;
    const int NS = I / 64;
    const int per_oblk = NS * 5120;
    int rem  = f;
    const int oblk = rem / per_oblk;  rem -= oblk * per_oblk;
    const int s    = rem / 5120;      rem -= s * 5120;
    const int p    = rem >> 10;
    const int l    = (rem & 1023) >> 4;
    const int j    = rem & 15;
    const int quad = l >> 4, col = l & 15;
    const float wv = w[(size_t)(oblk*16 + col) * I + s*64 + quad*16 + j];
    long long v = llrint((double)wv * 274877906944.0);   // w * 2^38, exact int
    int d = 0;
    for (int q = 0; q <= p; ++q) {                       // balanced base-256
        d = (int)((v + 128) & 255) - 128;
        v = (v - d) >> 8;
    }
    planes[f] = (signed char)d;
}

// ====================== fused gemm+conv kernel ==============================
// grid (B, O/16): b = blockIdx.x (fastest) so same-oblk blocks are
// dispatch-adjacent (A-planes stay L2-hot). Per block: barrier-free i8 MFMA
// gemm over all 256 t -> exact fp64 a in LDS -> 61-tap FIR conv -> u stores.
template<int I>
__global__ __launch_bounds__(256)
void fused_gc(const uint32_t*    __restrict__ bitsT,   // [B][I/32][256]
              const signed char* __restrict__ planes,  // swizzled A planes
              double*            __restrict__ u,       // [B][256][OS]
              int OS)
{
    constexpr int IW = I / 32;
    constexpr int NS = I / 64;
    __shared__ double a_lds[257 * 17];                   // 34.95 KB (row 256 = 0)
    __shared__ double srmE[68];

    const int tid  = threadIdx.x;
    const int lane = tid & 63;
    const int wvu  = tid >> 6;
    const int quad = lane >> 4;
    const int col  = lane & 15;
    const int b    = blockIdx.x;
    const int oblk = blockIdx.y;
    const int o0   = oblk * 16;
    const int tw   = wvu * 64;

    if (tid < 68) {
        const int k = tid - 2;
        double v = 0.0;
        if (k >= 1 && k <= 61) {
            double wv = (double)k / 8.0 * exp(1.0 - (double)k / 8.0);
            v = (double)(float)wv;     // fp32-rounded tap, widened (R1-R11)
        }
        srmE[tid] = v;
    }

    // ---------------- gemm: 5 i8 digit planes, K=64, NO barriers ------------
    const signed char* Apg = planes + (size_t)oblk * NS * 5120 + lane * 16;
    const uint32_t*    bw  = bitsT + (size_t)b * IW * 256 + tw + col;

    v4i acc[5][4];
    #pragma unroll
    for (int p = 0; p < 5; ++p)
        #pragma unroll
        for (int nt = 0; nt < 4; ++nt)
            acc[p][nt] = (v4i){0, 0, 0, 0};

    #pragma unroll 2
    for (int s = 0; s < NS; ++s) {
        uint32_t m0[4], m1[4];
        #pragma unroll
        for (int nt = 0; nt < 4; ++nt) {
            m0[nt] = bw[(size_t)(2*s)     * 256 + nt * 16];
            m1[nt] = bw[(size_t)(2*s + 1) * 256 + nt * 16];
        }
        v4i af[5];
        #pragma unroll
        for (int p = 0; p < 5; ++p)
            af[p] = *(const v4i*)(const void*)(Apg + (size_t)s * 5120 + p * 1024);

        #pragma unroll
        for (int nt = 0; nt < 4; ++nt) {
            const uint32_t sel = (quad & 2) ? m1[nt] : m0[nt];
            const uint32_t h   = (sel >> ((quad & 1) * 16)) & 0xFFFFu;
            union { uint32_t uu[4]; v4i v; } bf;
            #pragma unroll
            for (int j = 0; j < 4; ++j) {
                const uint32_t n = (h >> (4*j)) & 0xFu;
                bf.uu[j] = (n * 0x00204081u) & 0x01010101u;  // 4 bits -> 4 i8 {0,1}
            }
            #pragma unroll
            for (int p = 0; p < 5; ++p)
                acc[p][nt] = __builtin_amdgcn_mfma_i32_16x16x64_i8(
                                 af[p], bf.v, acc[p][nt], 0, 0, 0);
        }
    }

    // ---------------- recombine: exact fp64 a into LDS (verified) -----------
    const double inv = 1.0 / 274877906944.0;             // 2^-38
    #pragma unroll
    for (int nt = 0; nt < 4; ++nt) {
        const int t = tw + nt*16 + col;
        #pragma unroll
        for (int r = 0; r < 4; ++r) {
            double v =            (double)acc[4][nt][r];
            v = v * 256.0 + (double)acc[3][nt][r];
            v = v * 256.0 + (double)acc[2][nt][r];
            v = v * 256.0 + (double)acc[1][nt][r];
            v = v * 256.0 + (double)acc[0][nt][r];
            a_lds[t * 17 + quad*4 + r] = v * inv;
        }
    }
    if (tid < 17) a_lds[256 * 17 + tid] = 0.0;           // zero-guard row
    __syncthreads();                                     // the only barrier

    // ---------------- conv: 61-tap FIR from LDS (verified) ------------------
    const int o    = tid & 15;
    const int tgrp = tid >> 4;                           // 0..15
    #pragma unroll
    for (int pass = 0; pass < 4; ++pass) {
        const int T0b = pass * 64 + tgrp * 4;
        double u0 = 0, u1 = 0, u2 = 0, u3 = 0;
        double w1 = srmE[64], w2 = srmE[65], w3 = srmE[66];   // zero pads
        for (int d = 0; d < 64; d += 4) {
            const int row = T0b - 61 + d;
            const int r0 = (row + 0 < 0) ? 256 : row + 0;
            const int r1 = (row + 1 < 0) ? 256 : row + 1;
            const int r2 = (row + 2 < 0) ? 256 : row + 2;
            const int r3 = (row + 3 < 0) ? 256 : row + 3;
            const double av0 = a_lds[r0 * 17 + o];
            const double av1 = a_lds[r1 * 17 + o];
            const double av2 = a_lds[r2 * 17 + o];
            const double av3 = a_lds[r3 * 17 + o];
            const double n0 = srmE[63 - d], n1 = srmE[62 - d];
            const double n2 = srmE[61 - d], n3 = srmE[60 - d];
            u0 = fma(n0, av0, u0); u1 = fma(w1, av0, u1); u2 = fma(w2, av0, u2); u3 = fma(w3, av0, u3);
            u0 = fma(n1, av1, u0); u1 = fma(n0, av1, u1); u2 = fma(w1, av1, u2); u3 = fma(w2, av1, u3);
            u0 = fma(n2, av2, u0); u1 = fma(n1, av2, u1); u2 = fma(n0, av2, u2); u3 = fma(w1, av2, u3);
            u0 = fma(n3, av3, u0); u1 = fma(n2, av3, u1); u2 = fma(n1, av3, u2); u3 = fma(n0, av3, u3);
            w1 = n3; w2 = n2; w3 = n1;
        }
        double* up = u + ((size_t)b * 256 + T0b) * OS + o0 + o;
        up[0]              = u0;
        up[(size_t)OS]     = u1;
        up[(size_t)OS * 2] = u2;
        up[(size_t)OS * 3] = u3;
    }
}

// ========================== scan (R8/R10-verified) ==========================
// lane = neuron; 256 sequential steps; refractory via 61-bit history mask.
// FINAL=false: ballots -> bitsT_out[b][word][t]. FINAL=true: f32 out[b][o][t].
template<bool FINAL>
__global__ __launch_bounds__(256)
void scan_spikes(const double* __restrict__ u, uint32_t* __restrict__ bitsT_out,
                 float* __restrict__ f32_out, int OS, int OW)
{
    __shared__ double   ref64[KLEN];
    __shared__ uint32_t blds[8][256];   // 8 KB ballot staging
    const int tid = threadIdx.x;
    if (tid < KLEN) {
        double v = (double)tid / 8.0 * exp(1.0 - (double)tid / 8.0);
        ref64[tid] = (double)(float)(-20.0 * v);
    }
    __syncthreads();

    const int b     = blockIdx.y;
    const int obase = blockIdx.x * 256;
    const int o     = obase + tid;
    const int lane  = tid & 63;
    const int wv    = tid >> 6;
    const double* up = u + (size_t)b * TT * OS + o;

    uint64_t mask = 0;
    double cur0 = up[0], cur1 = up[OS], cur2 = up[2 * (size_t)OS], cur3 = up[3 * (size_t)OS];
    for (int t0 = 0; t0 < TT; t0 += 4) {
        double nx0 = 0, nx1 = 0, nx2 = 0, nx3 = 0;
        if (t0 + 4 < TT) {
            const double* pp = up + (size_t)(t0 + 4) * OS;
            nx0 = pp[0]; nx1 = pp[OS]; nx2 = pp[2 * (size_t)OS]; nx3 = pp[3 * (size_t)OS];
        }
        #pragma unroll
        for (int q = 0; q < 4; ++q) {
            const double uv = (q == 0) ? cur0 : (q == 1) ? cur1 : (q == 2) ? cur2 : cur3;
            uint64_t m = mask;
            double r0 = 0.0, r1 = 0.0;
            while (m) {
                int p = __builtin_ctzll(m); m &= m - 1;
                r0 += ref64[p + 1];
                if (m) { int pq = __builtin_ctzll(m); m &= m - 1; r1 += ref64[pq + 1]; }
            }
            const bool s = (uv + (r0 + r1)) >= THETA;
            const uint64_t bal = __ballot(s);
            if (lane == 0) {
                blds[wv * 2 + 0][t0 + q] = (uint32_t)bal;
                blds[wv * 2 + 1][t0 + q] = (uint32_t)(bal >> 32);
            }
            mask = ((mask << 1) | (s ? 1ull : 0ull)) & ((1ull << 61) - 1ull);
        }
        cur0 = nx0; cur1 = nx1; cur2 = nx2; cur3 = nx3;
    }
    __syncthreads();

    if (!FINAL) {
        const int wordbase = obase >> 5;
        for (int e = tid; e < 8 * 256; e += 256) {
            const int wl = e >> 8, t = e & 255;
            bitsT_out[((size_t)b * OW + wordbase + wl) * TT + t] = blds[wl][t];
        }
    } else {
        for (int ol = 0; ol < 256; ++ol) {
            const uint32_t w = blds[ol >> 5][tid];
            f32_out[((size_t)b * 512 + obase + ol) * TT + tid] =
                (float)((w >> (ol & 31)) & 1u);
        }
    }
}

// ================================ launcher ==================================
extern "C" void kernel_launch(void* const* d_in, const int* in_sizes, int n_in,
                              void* d_out, int out_size, void* d_ws, size_t ws_size,
                              hipStream_t stream)
{
    const float* x  = (const float*)d_in[0];   // [32][1024][256]
    const float* w1 = (const float*)d_in[1];   // [2048][1024]
    const float* w2 = (const float*)d_in[2];   // [512][2048]
    float* out = (float*)d_out;                // [32][512][256]

    char* ws = (char*)d_ws;
    uint32_t* bits1 = (uint32_t*)ws;                        // 1 MB
    uint32_t* bitsH = (uint32_t*)(ws + (size_t)1048576);    // 2 MB
    size_t off = 1048576 + 2097152;
    signed char* P1 = (signed char*)(ws + off);             // 128*16*5120 = 10.5 MB
    off += (size_t)128 * 16 * 5120;
    signed char* P2 = (signed char*)(ws + off);             // 32*32*5120  = 5.24 MB
    off += (size_t)32 * 32 * 5120;
    off = (off + 255) & ~(size_t)255;
    double* uBuf = (double*)(ws + off);                     // 32*256*2048*8 = 134 MB

    bitifyT<<<dim3(32, 8), 256, 0, stream>>>(x, bits1);
    decompose_i8<<<dim3((10485760 + 255)/256), 256, 0, stream>>>(w1, P1, 1024, 10485760);
    decompose_i8<<<dim3((5242880  + 255)/256), 256, 0, stream>>>(w2, P2, 2048, 5242880);

    // layer 1: 1024 -> 2048  (grid: b fastest, oblk slow -> A-planes L2-hot)
    fused_gc<1024><<<dim3(32, 128), 256, 0, stream>>>(bits1, P1, uBuf, 2048);
    scan_spikes<false><<<dim3(8, 32), 256, 0, stream>>>(uBuf, bitsH, nullptr, 2048, 64);
    // layer 2: 2048 -> 512
    fused_gc<2048><<<dim3(32, 32), 256, 0, stream>>>(bitsH, P2, uBuf, 512);
    scan_spikes<true><<<dim3(2, 32), 256, 0, stream>>>(uBuf, nullptr, out, 512, 16);
}